// Round 1
// baseline (2706.678 us; speedup 1.0000x reference)
//
#include <hip/hip_runtime.h>
#include <hip/hip_bf16.h>

#define NN 384
#define CC 128
#define HH 4
#define DD 32

// 1/sqrt(32)
#define QK_SCALE 0.17677669529663687f

// ---------------------------------------------------------------------------
// K1: LayerNorm over channel dim + pair-bias projection bias[h,i,j]
// one wave (64 lanes) per position p = i*N + j; 2 channels per lane
// ---------------------------------------------------------------------------
__global__ __launch_bounds__(256) void k_ln_bias(
    const float* __restrict__ pair, const float* __restrict__ ln_w,
    const float* __restrict__ ln_b, const float* __restrict__ bias_w,
    float* __restrict__ x, float* __restrict__ biasb) {
  const int wave = threadIdx.x >> 6;
  const int l = threadIdx.x & 63;
  const int p = blockIdx.x * 4 + wave;  // 0 .. N*N-1 (grid = N*N/4)

  const float* row = pair + (size_t)p * CC;
  const float v0 = row[l];
  const float v1 = row[l + 64];

  float s = v0 + v1;
  float sq = v0 * v0 + v1 * v1;
#pragma unroll
  for (int off = 32; off >= 1; off >>= 1) {
    s += __shfl_xor(s, off);
    sq += __shfl_xor(sq, off);
  }
  const float mean = s * (1.0f / 128.0f);
  const float var = sq * (1.0f / 128.0f) - mean * mean;
  const float rstd = rsqrtf(var + 1e-5f);

  const float x0 = (v0 - mean) * rstd * ln_w[l] + ln_b[l];
  const float x1 = (v1 - mean) * rstd * ln_w[l + 64] + ln_b[l + 64];
  x[(size_t)p * CC + l] = x0;
  x[(size_t)p * CC + 64 + l] = x1;

  // bias[h][p] = sum_c x_c * bias_w[h][c]
#pragma unroll
  for (int h = 0; h < HH; ++h) {
    float b = x0 * bias_w[h * CC + l] + x1 * bias_w[h * CC + 64 + l];
#pragma unroll
    for (int off = 32; off >= 1; off >>= 1) b += __shfl_xor(b, off);
    if (l == 0) biasb[h * NN * NN + p] = b;
  }
}

// ---------------------------------------------------------------------------
// K2: per-(row b, head h) attention. Computes q,k,v from x on the fly
// (weight slice rows h*32..h*32+31 only -> no redundant FLOPs), k/v staged
// in LDS, then per-query logits + wave softmax + PV.
// blockIdx.x = b*4 + h ; 512 threads = 8 waves
// ---------------------------------------------------------------------------
__global__ __launch_bounds__(512) void k_attn(
    const float* __restrict__ x, const float* __restrict__ biasb,
    const float* __restrict__ mask, const float* __restrict__ q_w,
    const float* __restrict__ k_w, const float* __restrict__ v_w,
    float* __restrict__ o) {
  __shared__ float ks[NN * 33];       // 50688 B  (pad 33 -> conflict-free)
  __shared__ float vs[NN * 33];       // 50688 B
  __shared__ float xt[32 * 128];      // 16384 B  x tile (reads are broadcast)
  __shared__ float qs[32 * 33];       // 4224 B   scaled q tile
  __shared__ float mb[NN];            // 1536 B   mask bias per key
  __shared__ float wbuf[8 * NN];      // 12288 B  per-wave softmax weights
  __shared__ __hip_bfloat16 kw[DD * 132];  // 8448 B each
  __shared__ __hip_bfloat16 vw[DD * 132];
  __shared__ __hip_bfloat16 qw[DD * 132];
  // total ~161 KB < 160 KiB (163840 B)

  const int b = blockIdx.x >> 2;
  const int h = blockIdx.x & 3;
  const int t = threadIdx.x;
  const int w = t >> 6;
  const int l = t & 63;

  // load per-head weight slices (rows h*32 .. h*32+31), bf16 in LDS
  for (int idx = t; idx < DD * CC; idx += 512) {
    const int r = idx >> 7, c = idx & 127;
    kw[r * 132 + c] = __float2bfloat16(k_w[(h * DD + r) * CC + c]);
    vw[r * 132 + c] = __float2bfloat16(v_w[(h * DD + r) * CC + c]);
    qw[r * 132 + c] = __float2bfloat16(q_w[(h * DD + r) * CC + c]);
  }
  if (t < NN) mb[t] = 1e9f * (mask[b * NN + t] - 1.0f);

  const int d = t & 31;        // 0..31
  const int r2 = t >> 5;       // 0..15

  // ---- Phase B: k, v for all 384 keys of row b ----
  for (int jt = 0; jt < 12; ++jt) {
    __syncthreads();
    for (int idx = t; idx < 32 * CC; idx += 512) {
      const int r = idx >> 7, c = idx & 127;
      xt[r * 128 + c] = x[((size_t)b * NN + jt * 32 + r) * CC + c];
    }
    __syncthreads();
    float k0 = 0, k1 = 0, v0 = 0, v1 = 0;
#pragma unroll 4
    for (int c = 0; c < CC; ++c) {
      const float xa = xt[r2 * 128 + c];
      const float xb = xt[(r2 + 16) * 128 + c];
      const float kk = __bfloat162float(kw[d * 132 + c]);
      const float vv = __bfloat162float(vw[d * 132 + c]);
      k0 = fmaf(xa, kk, k0);
      k1 = fmaf(xb, kk, k1);
      v0 = fmaf(xa, vv, v0);
      v1 = fmaf(xb, vv, v1);
    }
    const int j0 = jt * 32;
    ks[(j0 + r2) * 33 + d] = k0;
    ks[(j0 + r2 + 16) * 33 + d] = k1;
    vs[(j0 + r2) * 33 + d] = v0;
    vs[(j0 + r2 + 16) * 33 + d] = v1;
  }

  // ---- Phase C: queries, 12 tiles of 32 ----
  for (int it = 0; it < 12; ++it) {
    __syncthreads();  // also makes ks/vs (and weights) visible on first iter
    for (int idx = t; idx < 32 * CC; idx += 512) {
      const int r = idx >> 7, c = idx & 127;
      xt[r * 128 + c] = x[((size_t)b * NN + it * 32 + r) * CC + c];
    }
    __syncthreads();
    {  // q tile (pre-scaled)
      float q0 = 0, q1 = 0;
#pragma unroll 4
      for (int c = 0; c < CC; ++c) {
        const float qq = __bfloat162float(qw[d * 132 + c]);
        q0 = fmaf(xt[r2 * 128 + c], qq, q0);
        q1 = fmaf(xt[(r2 + 16) * 128 + c], qq, q1);
      }
      qs[r2 * 33 + d] = q0 * QK_SCALE;
      qs[(r2 + 16) * 33 + d] = q1 * QK_SCALE;
    }
    __syncthreads();

    for (int qi = 0; qi < 4; ++qi) {
      const int il = qi * 8 + w;  // 0..31
      const int i = it * 32 + il;

      float acc[6] = {0, 0, 0, 0, 0, 0};
#pragma unroll
      for (int dd2 = 0; dd2 < 32; ++dd2) {
        const float qd = qs[il * 33 + dd2];
#pragma unroll
        for (int jj = 0; jj < 6; ++jj)
          acc[jj] = fmaf(qd, ks[(jj * 64 + l) * 33 + dd2], acc[jj]);
      }
      const float* brow = biasb + ((size_t)h * NN + i) * NN;
      float m = -3.4e38f;
#pragma unroll
      for (int jj = 0; jj < 6; ++jj) {
        acc[jj] += brow[jj * 64 + l] + mb[jj * 64 + l];
        m = fmaxf(m, acc[jj]);
      }
#pragma unroll
      for (int off = 32; off >= 1; off >>= 1) m = fmaxf(m, __shfl_xor(m, off));
      float s = 0;
#pragma unroll
      for (int jj = 0; jj < 6; ++jj) {
        acc[jj] = __expf(acc[jj] - m);
        s += acc[jj];
      }
#pragma unroll
      for (int off = 32; off >= 1; off >>= 1) s += __shfl_xor(s, off);
      const float inv = 1.0f / s;

#pragma unroll
      for (int jj = 0; jj < 6; ++jj) wbuf[w * NN + jj * 64 + l] = acc[jj];

      // PV: lane l handles channel d = l&31 over half of the keys
      const int dch = l & 31;
      const int half = l >> 5;
      float oacc = 0;
#pragma unroll 8
      for (int jx = 0; jx < 192; ++jx) {
        const int j = half * 192 + jx;
        oacc = fmaf(wbuf[w * NN + j], vs[j * 33 + dch], oacc);
      }
      oacc += __shfl_xor(oacc, 32);
      if (l < 32)
        o[((size_t)b * NN + i) * CC + h * DD + dch] = oacc * inv;
    }
  }
}

// ---------------------------------------------------------------------------
// K3: out = (sigmoid(x @ g_w^T) * o) @ o_w^T, 32 rows per block.
// xt/at share one LDS union so both weight matrices stay fp32.
// ---------------------------------------------------------------------------
__global__ __launch_bounds__(512) void k_gate_out(
    const float* __restrict__ x, const float* __restrict__ o,
    const float* __restrict__ g_w, const float* __restrict__ o_w,
    float* __restrict__ out) {
  __shared__ float gw[CC * 129];   // 66048 B
  __shared__ float ow[CC * 129];   // 66048 B
  __shared__ float xa[32 * 130];   // 16640 B: xt in phase 1, at in phase 2
  // total ~148.7 KB

  const int t = threadIdx.x;
  const size_t row0 = (size_t)blockIdx.x * 32;

  for (int idx = t; idx < CC * CC; idx += 512) {
    const int r = idx >> 7, c = idx & 127;
    gw[r * 129 + c] = g_w[idx];
    ow[r * 129 + c] = o_w[idx];
  }
  for (int idx = t; idx < 32 * CC; idx += 512) {
    const int r = idx >> 7, c = idx & 127;
    xa[r * 130 + c] = x[(row0 + r) * CC + c];
  }
  __syncthreads();

  const int c0 = (t & 63) * 2;   // 2 consecutive output cols
  const int rg = (t >> 6) * 4;   // 4 rows

  float a[8] = {0, 0, 0, 0, 0, 0, 0, 0};
  for (int k = 0; k < CC; ++k) {
    const float w0 = gw[c0 * 129 + k];
    const float w1 = gw[(c0 + 1) * 129 + k];
#pragma unroll
    for (int rr = 0; rr < 4; ++rr) {
      const float xv = xa[(rg + rr) * 130 + k];
      a[rr * 2] = fmaf(xv, w0, a[rr * 2]);
      a[rr * 2 + 1] = fmaf(xv, w1, a[rr * 2 + 1]);
    }
  }
  __syncthreads();  // all xt reads done before overwriting with at
#pragma unroll
  for (int rr = 0; rr < 4; ++rr) {
#pragma unroll
    for (int cc2 = 0; cc2 < 2; ++cc2) {
      const float g = 1.0f / (1.0f + __expf(-a[rr * 2 + cc2]));
      xa[(rg + rr) * 130 + c0 + cc2] =
          g * o[(row0 + rg + rr) * CC + c0 + cc2];
    }
  }
  __syncthreads();

  float bacc[8] = {0, 0, 0, 0, 0, 0, 0, 0};
  for (int k = 0; k < CC; ++k) {
    const float w0 = ow[c0 * 129 + k];
    const float w1 = ow[(c0 + 1) * 129 + k];
#pragma unroll
    for (int rr = 0; rr < 4; ++rr) {
      const float av = xa[(rg + rr) * 130 + k];
      bacc[rr * 2] = fmaf(av, w0, bacc[rr * 2]);
      bacc[rr * 2 + 1] = fmaf(av, w1, bacc[rr * 2 + 1]);
    }
  }
#pragma unroll
  for (int rr = 0; rr < 4; ++rr) {
#pragma unroll
    for (int cc2 = 0; cc2 < 2; ++cc2)
      out[(row0 + rg + rr) * CC + c0 + cc2] = bacc[rr * 2 + cc2];
  }
}

// ---------------------------------------------------------------------------
extern "C" void kernel_launch(void* const* d_in, const int* in_sizes, int n_in,
                              void* d_out, int out_size, void* d_ws,
                              size_t ws_size, hipStream_t stream) {
  const float* pair = (const float*)d_in[0];
  const float* mask = (const float*)d_in[1];
  const float* ln_w = (const float*)d_in[2];
  const float* ln_b = (const float*)d_in[3];
  const float* bias_w = (const float*)d_in[4];
  const float* q_w = (const float*)d_in[5];
  const float* k_w = (const float*)d_in[6];
  const float* v_w = (const float*)d_in[7];
  const float* g_w = (const float*)d_in[8];
  const float* o_w = (const float*)d_in[9];

  float* ws = (float*)d_ws;
  float* x = ws;                                   // [N,N,C]
  float* biasb = x + (size_t)NN * NN * CC;         // [H,N,N]
  float* o = biasb + (size_t)HH * NN * NN;         // [N,N,C]
  float* out = (float*)d_out;
  // ws usage: (2*N*N*C + H*N*N) * 4 B ~= 153.4 MB

  hipLaunchKernelGGL(k_ln_bias, dim3(NN * NN / 4), dim3(256), 0, stream, pair,
                     ln_w, ln_b, bias_w, x, biasb);
  hipLaunchKernelGGL(k_attn, dim3(NN * HH), dim3(512), 0, stream, x, biasb,
                     mask, q_w, k_w, v_w, o);
  hipLaunchKernelGGL(k_gate_out, dim3(NN * NN / 32), dim3(512), 0, stream, x,
                     o, g_w, o_w, out);
}

// Round 3
// 554.936 us; speedup vs baseline: 4.8775x; 4.8775x over previous
//
#include <hip/hip_runtime.h>
#include <hip/hip_bf16.h>

#define NN 384
#define CC 128
#define HH 4
#define DD 32
#define QK_SCALE 0.17677669529663687f

typedef float f32x4 __attribute__((ext_vector_type(4)));
typedef short s16x8 __attribute__((ext_vector_type(8)));
typedef unsigned short u16;

__device__ __forceinline__ u16 f2b(float f) {
  union { float f; unsigned u; } c; c.f = f;
  unsigned u = c.u + 0x7FFFu + ((c.u >> 16) & 1u);
  return (u16)(u >> 16);
}

#define MFMA16(a, b, c) __builtin_amdgcn_mfma_f32_16x16x32_bf16((a), (b), (c), 0, 0, 0)

// ---------------------------------------------------------------------------
// K1: LayerNorm + pair-bias. One wave per position p; lane handles channels
// 2l, 2l+1. Writes x as packed bf16, bias as fp32.
// ---------------------------------------------------------------------------
__global__ __launch_bounds__(256) void k_ln_bias(
    const float* __restrict__ pair, const float* __restrict__ ln_w,
    const float* __restrict__ ln_b, const float* __restrict__ bias_w,
    u16* __restrict__ xb, float* __restrict__ biasb) {
  const int wave = threadIdx.x >> 6;
  const int l = threadIdx.x & 63;
  const int p = blockIdx.x * 4 + wave;

  const float2 v = ((const float2*)pair)[(size_t)p * 64 + l];
  float s = v.x + v.y, sq = v.x * v.x + v.y * v.y;
#pragma unroll
  for (int off = 32; off >= 1; off >>= 1) {
    s += __shfl_xor(s, off);
    sq += __shfl_xor(sq, off);
  }
  const float mean = s * (1.0f / 128.0f);
  const float rstd = rsqrtf(sq * (1.0f / 128.0f) - mean * mean + 1e-5f);
  const float2 lw = ((const float2*)ln_w)[l];
  const float2 lb2 = ((const float2*)ln_b)[l];
  const float x0 = (v.x - mean) * rstd * lw.x + lb2.x;
  const float x1 = (v.y - mean) * rstd * lw.y + lb2.y;
  ((unsigned*)xb)[(size_t)p * 64 + l] =
      (unsigned)f2b(x0) | ((unsigned)f2b(x1) << 16);

#pragma unroll
  for (int h = 0; h < HH; ++h) {
    const float2 bw = ((const float2*)bias_w)[h * 64 + l];
    float bp = x0 * bw.x + x1 * bw.y;
#pragma unroll
    for (int off = 32; off >= 1; off >>= 1) bp += __shfl_xor(bp, off);
    if (l == 0) biasb[(size_t)h * NN * NN + p] = bp;
  }
}

// ---------------------------------------------------------------------------
// K2: QKV projection GEMM. M-tile 128 (rows within one b), N=384 (q|k|v),
// K=128. q pre-scaled. q,k stored [bh][384][32]; v stored transposed
// [bh][32][384] so K3's PV B-fragments are contiguous.
// ---------------------------------------------------------------------------
__global__ __launch_bounds__(512) void k_qkv(
    const u16* __restrict__ xb, const float* __restrict__ q_w,
    const float* __restrict__ k_w, const float* __restrict__ v_w,
    u16* __restrict__ qg, u16* __restrict__ kg, u16* __restrict__ vtg) {
  __shared__ u16 wsh[384][136];  // 104448 B
  __shared__ u16 xs[128][136];   // 34816 B
  const int t = threadIdx.x;
  const int row0 = blockIdx.x * 128;

  for (int idx = t; idx < 384 * 64; idx += 512) {
    const int n = idx >> 6, cp = idx & 63;
    float2 vv;
    if (n < 128) {
      vv = ((const float2*)q_w)[n * 64 + cp];
      vv.x *= QK_SCALE;
      vv.y *= QK_SCALE;
    } else if (n < 256) {
      vv = ((const float2*)k_w)[(n - 128) * 64 + cp];
    } else {
      vv = ((const float2*)v_w)[(n - 256) * 64 + cp];
    }
    ((unsigned*)&wsh[n][0])[cp] =
        (unsigned)f2b(vv.x) | ((unsigned)f2b(vv.y) << 16);
  }
  for (int idx = t; idx < 128 * 64; idx += 512) {
    const int r = idx >> 6, cp = idx & 63;
    ((unsigned*)&xs[r][0])[cp] = ((const unsigned*)xb)[((size_t)row0 + r) * 64 + cp];
  }
  __syncthreads();

  const int w = t >> 6, l = t & 63;
  const int m0 = (w >> 2) * 64, n0 = (w & 3) * 96;
  const int lr = l & 15, lg = l >> 4;

  f32x4 acc[4][6];
#pragma unroll
  for (int ms = 0; ms < 4; ++ms)
#pragma unroll
    for (int ns = 0; ns < 6; ++ns) acc[ms][ns] = (f32x4){0.f, 0.f, 0.f, 0.f};

#pragma unroll
  for (int ks = 0; ks < 4; ++ks) {
    s16x8 a[4], bb[6];
#pragma unroll
    for (int ms = 0; ms < 4; ++ms)
      a[ms] = *(const s16x8*)&xs[m0 + ms * 16 + lr][ks * 32 + lg * 8];
#pragma unroll
    for (int ns = 0; ns < 6; ++ns)
      bb[ns] = *(const s16x8*)&wsh[n0 + ns * 16 + lr][ks * 32 + lg * 8];
#pragma unroll
    for (int ms = 0; ms < 4; ++ms)
#pragma unroll
      for (int ns = 0; ns < 6; ++ns)
        acc[ms][ns] = MFMA16(a[ms], bb[ns], acc[ms][ns]);
  }

  const int b = blockIdx.x / 3;
  const int jbase = (blockIdx.x % 3) * 128;
#pragma unroll
  for (int ms = 0; ms < 4; ++ms) {
    const int jl = jbase + m0 + ms * 16 + lg * 4;
#pragma unroll
    for (int ns = 0; ns < 6; ++ns) {
      const int n = n0 + ns * 16 + lr;
      const int h = (n >> 5) & 3, d = n & 31;
      const size_t bh = (size_t)(b * 4 + h);
      if (n < 256) {
        u16* dst = (n < 128 ? qg : kg) + bh * 384 * 32;
#pragma unroll
        for (int r = 0; r < 4; ++r) dst[(jl + r) * 32 + d] = f2b(acc[ms][ns][r]);
      } else {
        unsigned* dst = (unsigned*)vtg + (bh * 32 + d) * 192;
#pragma unroll
        for (int r = 0; r < 4; r += 2)
          dst[(jl >> 1) + (r >> 1)] = (unsigned)f2b(acc[ms][ns][r]) |
                                      ((unsigned)f2b(acc[ms][ns][r + 1]) << 16);
      }
    }
  }
}

// ---------------------------------------------------------------------------
// K3: flash attention per (b,h). 8 waves x 48 queries. K,Vt in LDS; Q frags
// from global; online softmax; P via per-wave LDS round-trip; o -> d_out fp32.
// ---------------------------------------------------------------------------
__global__ __launch_bounds__(512) void k_attn(
    const u16* __restrict__ qg, const u16* __restrict__ kg,
    const u16* __restrict__ vtg, const float* __restrict__ biasb,
    const float* __restrict__ mask, float* __restrict__ o_out) {
  __shared__ u16 Ks[384][40];    // 30720 B
  __shared__ u16 Vts[32][392];   // 25088 B
  __shared__ u16 Ps[8 * 48 * 72];  // 55296 B
  __shared__ float mb[NN];       // 1536 B

  const int bid = blockIdx.x;
  const int b = bid >> 2, h = bid & 3;
  const size_t bh = (size_t)bid;
  const int t = threadIdx.x, w = t >> 6, l = t & 63;
  const int lr = l & 15, lg = l >> 4;

  const unsigned* ksrc = (const unsigned*)(kg + bh * 12288);
  for (int idx = t; idx < 6144; idx += 512)
    ((unsigned*)&Ks[0][0])[(idx >> 4) * 20 + (idx & 15)] = ksrc[idx];
  {
    const unsigned* vsrc = (const unsigned*)(vtg + bh * 12288);
    const int d = t >> 4;
#pragma unroll
    for (int rep = 0; rep < 12; ++rep) {
      const int jp = (t & 15) + rep * 16;
      ((unsigned*)&Vts[0][0])[d * 196 + jp] = vsrc[d * 192 + jp];
    }
  }
  if (t < NN) mb[t] = 1e9f * (mask[b * NN + t] - 1.0f);

  const int q0 = w * 48;
  s16x8 aQ[3];
#pragma unroll
  for (int ms = 0; ms < 3; ++ms)
    aQ[ms] = *(const s16x8*)(qg + bh * 12288 +
                             ((size_t)(q0 + ms * 16 + lr)) * 32 + lg * 8);
  __syncthreads();

  float mr[3][4], lsum[3][4];
  f32x4 oa[3][2];
#pragma unroll
  for (int ms = 0; ms < 3; ++ms) {
#pragma unroll
    for (int r = 0; r < 4; ++r) {
      mr[ms][r] = -3.0e38f;
      lsum[ms][r] = 0.f;
    }
#pragma unroll
    for (int ns = 0; ns < 2; ++ns) oa[ms][ns] = (f32x4){0.f, 0.f, 0.f, 0.f};
  }

  u16* Pw = &Ps[w * 3456];
  const float* bbase = biasb + (size_t)h * NN * NN;
  const f32x4 zero4 = {0.f, 0.f, 0.f, 0.f};

  for (int kt = 0; kt < 6; ++kt) {
    f32x4 s[3][4];
    s16x8 bK[4];
#pragma unroll
    for (int js = 0; js < 4; ++js)
      bK[js] = *(const s16x8*)&Ks[kt * 64 + js * 16 + lr][lg * 8];
#pragma unroll
    for (int ms = 0; ms < 3; ++ms)
#pragma unroll
      for (int js = 0; js < 4; ++js)
        s[ms][js] = MFMA16(aQ[ms], bK[js], zero4);

    // bias + mask add
    const int jb = kt * 64 + lr;
#pragma unroll
    for (int ms = 0; ms < 3; ++ms) {
      const int i0 = q0 + ms * 16 + lg * 4;
#pragma unroll
      for (int js = 0; js < 4; ++js) {
        const int j = jb + js * 16;
        const float mbj = mb[j];
#pragma unroll
        for (int r = 0; r < 4; ++r)
          s[ms][js][r] += bbase[(size_t)(i0 + r) * NN + j] + mbj;
      }
    }

    // online softmax (rows live in 16-lane groups)
#pragma unroll
    for (int ms = 0; ms < 3; ++ms) {
#pragma unroll
      for (int r = 0; r < 4; ++r) {
        float tm = fmaxf(fmaxf(s[ms][0][r], s[ms][1][r]),
                         fmaxf(s[ms][2][r], s[ms][3][r]));
        tm = fmaxf(tm, __shfl_xor(tm, 1));
        tm = fmaxf(tm, __shfl_xor(tm, 2));
        tm = fmaxf(tm, __shfl_xor(tm, 4));
        tm = fmaxf(tm, __shfl_xor(tm, 8));
        const float nm = fmaxf(mr[ms][r], tm);
        const float sc = __expf(mr[ms][r] - nm);
        mr[ms][r] = nm;
        float ts = 0.f;
#pragma unroll
        for (int js = 0; js < 4; ++js) {
          const float p = __expf(s[ms][js][r] - nm);
          s[ms][js][r] = p;
          ts += p;
        }
        ts += __shfl_xor(ts, 1);
        ts += __shfl_xor(ts, 2);
        ts += __shfl_xor(ts, 4);
        ts += __shfl_xor(ts, 8);
        lsum[ms][r] = lsum[ms][r] * sc + ts;
        oa[ms][0][r] *= sc;
        oa[ms][1][r] *= sc;
      }
    }

    // P -> LDS (bf16), per-wave buffer
#pragma unroll
    for (int ms = 0; ms < 3; ++ms)
#pragma unroll
      for (int js = 0; js < 4; ++js)
#pragma unroll
        for (int r = 0; r < 4; ++r)
          Pw[(ms * 16 + lg * 4 + r) * 72 + js * 16 + lr] = f2b(s[ms][js][r]);

    // PV
#pragma unroll
    for (int ks = 0; ks < 2; ++ks) {
      s16x8 pa[3], bv[2];
#pragma unroll
      for (int ms = 0; ms < 3; ++ms)
        pa[ms] = *(const s16x8*)&Pw[(ms * 16 + lr) * 72 + ks * 32 + lg * 8];
#pragma unroll
      for (int ns = 0; ns < 2; ++ns)
        bv[ns] = *(const s16x8*)&Vts[ns * 16 + lr][kt * 64 + ks * 32 + lg * 8];
#pragma unroll
      for (int ms = 0; ms < 3; ++ms)
#pragma unroll
        for (int ns = 0; ns < 2; ++ns)
          oa[ms][ns] = MFMA16(pa[ms], bv[ns], oa[ms][ns]);
    }
  }

  // epilogue: normalize, write o (fp32) into d_out
#pragma unroll
  for (int ms = 0; ms < 3; ++ms) {
#pragma unroll
    for (int r = 0; r < 4; ++r) {
      const float inv = 1.0f / lsum[ms][r];
      const size_t row = (size_t)b * NN + q0 + ms * 16 + lg * 4 + r;
#pragma unroll
      for (int ns = 0; ns < 2; ++ns)
        o_out[row * CC + h * DD + ns * 16 + lr] = oa[ms][ns][r] * inv;
    }
  }
}

// ---------------------------------------------------------------------------
// K4: out = (sigmoid(x@g_w^T) * o) @ o_w^T. Reads its own o-tile from d_out,
// overwrites it after a barrier (block-local 128-row tile).
// ---------------------------------------------------------------------------
__global__ __launch_bounds__(512) void k_gate_out(
    const u16* __restrict__ xb, const float* __restrict__ g_w,
    const float* __restrict__ o_w, float* __restrict__ io) {
  __shared__ u16 gws[128][136];
  __shared__ u16 ows[128][136];
  __shared__ u16 xs[128][136];
  __shared__ u16 as_[128][136];

  const int t = threadIdx.x;
  const int row0 = blockIdx.x * 128;

  for (int idx = t; idx < 128 * 64; idx += 512) {
    const int n = idx >> 6, cp = idx & 63;
    const float2 g2 = ((const float2*)g_w)[idx];
    const float2 o2 = ((const float2*)o_w)[idx];
    ((unsigned*)&gws[n][0])[cp] =
        (unsigned)f2b(g2.x) | ((unsigned)f2b(g2.y) << 16);
    ((unsigned*)&ows[n][0])[cp] =
        (unsigned)f2b(o2.x) | ((unsigned)f2b(o2.y) << 16);
    ((unsigned*)&xs[n][0])[cp] = ((const unsigned*)xb)[((size_t)row0 + n) * 64 + cp];
  }
  __syncthreads();

  const int w = t >> 6, l = t & 63;
  const int m0 = (w >> 2) * 64, n0 = (w & 3) * 32;
  const int lr = l & 15, lg = l >> 4;

  f32x4 acc[4][2];
#pragma unroll
  for (int ms = 0; ms < 4; ++ms)
#pragma unroll
    for (int ns = 0; ns < 2; ++ns) acc[ms][ns] = (f32x4){0.f, 0.f, 0.f, 0.f};

#pragma unroll
  for (int ks = 0; ks < 4; ++ks) {
    s16x8 a[4], bb[2];
#pragma unroll
    for (int ms = 0; ms < 4; ++ms)
      a[ms] = *(const s16x8*)&xs[m0 + ms * 16 + lr][ks * 32 + lg * 8];
#pragma unroll
    for (int ns = 0; ns < 2; ++ns)
      bb[ns] = *(const s16x8*)&gws[n0 + ns * 16 + lr][ks * 32 + lg * 8];
#pragma unroll
    for (int ms = 0; ms < 4; ++ms)
#pragma unroll
      for (int ns = 0; ns < 2; ++ns)
        acc[ms][ns] = MFMA16(a[ms], bb[ns], acc[ms][ns]);
  }

  // gate * o -> as_ (bf16)
#pragma unroll
  for (int ms = 0; ms < 4; ++ms) {
#pragma unroll
    for (int ns = 0; ns < 2; ++ns) {
#pragma unroll
      for (int r = 0; r < 4; ++r) {
        const int mloc = m0 + ms * 16 + lg * 4 + r;
        const int gcol = n0 + ns * 16 + lr;
        const float ov = io[((size_t)row0 + mloc) * CC + gcol];
        const float gate = 1.0f / (1.0f + __expf(-acc[ms][ns][r]));
        as_[mloc][gcol] = f2b(gate * ov);
      }
    }
  }
  __syncthreads();

  f32x4 acc2[4][2];
#pragma unroll
  for (int ms = 0; ms < 4; ++ms)
#pragma unroll
    for (int ns = 0; ns < 2; ++ns) acc2[ms][ns] = (f32x4){0.f, 0.f, 0.f, 0.f};

#pragma unroll
  for (int ks = 0; ks < 4; ++ks) {
    s16x8 a[4], bb[2];
#pragma unroll
    for (int ms = 0; ms < 4; ++ms)
      a[ms] = *(const s16x8*)&as_[m0 + ms * 16 + lr][ks * 32 + lg * 8];
#pragma unroll
    for (int ns = 0; ns < 2; ++ns)
      bb[ns] = *(const s16x8*)&ows[n0 + ns * 16 + lr][ks * 32 + lg * 8];
#pragma unroll
    for (int ms = 0; ms < 4; ++ms)
#pragma unroll
      for (int ns = 0; ns < 2; ++ns)
        acc2[ms][ns] = MFMA16(a[ms], bb[ns], acc2[ms][ns]);
  }

#pragma unroll
  for (int ms = 0; ms < 4; ++ms)
#pragma unroll
    for (int ns = 0; ns < 2; ++ns)
#pragma unroll
      for (int r = 0; r < 4; ++r)
        io[((size_t)row0 + m0 + ms * 16 + lg * 4 + r) * CC + n0 + ns * 16 + lr] =
            acc2[ms][ns][r];
}

// ---------------------------------------------------------------------------
extern "C" void kernel_launch(void* const* d_in, const int* in_sizes, int n_in,
                              void* d_out, int out_size, void* d_ws,
                              size_t ws_size, hipStream_t stream) {
  const float* pair = (const float*)d_in[0];
  const float* mask = (const float*)d_in[1];
  const float* ln_w = (const float*)d_in[2];
  const float* ln_b = (const float*)d_in[3];
  const float* bias_w = (const float*)d_in[4];
  const float* q_w = (const float*)d_in[5];
  const float* k_w = (const float*)d_in[6];
  const float* v_w = (const float*)d_in[7];
  const float* g_w = (const float*)d_in[8];
  const float* o_w = (const float*)d_in[9];

  char* wsb = (char*)d_ws;
  u16* xb = (u16*)wsb;                          // 147456*128*2   = 37,748,736
  float* biasb = (float*)(wsb + 37748736);      // 4*384*384*4    =  2,359,296
  u16* qg = (u16*)(wsb + 40108032);             // 1536*384*32*2  = 37,748,736
  u16* kg = (u16*)(wsb + 77856768);             // same
  u16* vtg = (u16*)(wsb + 115605504);           // same -> ends 153,354,240
  float* io = (float*)d_out;

  hipLaunchKernelGGL(k_ln_bias, dim3(NN * NN / 4), dim3(256), 0, stream, pair,
                     ln_w, ln_b, bias_w, xb, biasb);
  hipLaunchKernelGGL(k_qkv, dim3(1152), dim3(512), 0, stream, xb, q_w, k_w,
                     v_w, qg, kg, vtg);
  hipLaunchKernelGGL(k_attn, dim3(NN * HH), dim3(512), 0, stream, qg, kg, vtg,
                     biasb, mask, io);
  hipLaunchKernelGGL(k_gate_out, dim3(1152), dim3(512), 0, stream, xb, g_w,
                     o_w, io);
}